// Round 1
// 390.660 us; speedup vs baseline: 1.1603x; 1.1603x over previous
//
#include <hip/hip_runtime.h>
#include <hip/hip_bf16.h>

// LSTM_single_task: B=32768, I=H=512. Live math: 3 gate GEMMs (i,c,o) over
// u=[x,h] (K=1024), fused activations. f-gate and c_prev are dead code.
//
// R3: m97-structure GEMM. Changes vs R2 (453 us, gemm dispatch 240 us,
// MfmaUtil 17.8%, 1.05e7 LDS bank conflicts, FETCH 529 MB):
//  - pack_u: one-time fp32->bf16 prepack of U=[x|h] (64 MB in workspace).
//    Removes per-iter cvt VALU + enables global_load_lds staging.
//  - lstm_gemm_v2: BK=64 (half the barrier drains), global_load_lds
//    width-16 for A and B, XOR-swizzled LDS (pre-swizzled global source +
//    swizzled ds_read: 2-way conflicts = free), XCD-chunked block swizzle
//    (panel L2 reuse; 2048 blocks % 8 == 0 so simple form is bijective).
//  - Fallback to the R2 kernel if ws_size < 70.3 MB (U doesn't fit).

typedef unsigned short u16;
typedef u16 u16x8 __attribute__((ext_vector_type(8)));
typedef __bf16 bf16x8 __attribute__((ext_vector_type(8)));
typedef float f32x4 __attribute__((ext_vector_type(4)));

#define B_DIM 32768
#define H_DIM 512
#define K_DIM 1024
#define BH_ELEMS (B_DIM * H_DIM)          // 16,777,216
#define U_ELEMS ((long)B_DIM * K_DIM)     // 33,554,432
#define WT_BYTES (3u * 512u * 1024u * 2u) // 3,145,728
#define U_BYTES ((size_t)U_ELEMS * 2u)    // 67,108,864

#define GLOBAL_AS(p) ((__attribute__((address_space(1))) void*)(p))
#define LDS_AS(p)    ((__attribute__((address_space(3))) void*)(p))

__device__ __forceinline__ float bf2f(u16 u) {
    unsigned v = ((unsigned)u) << 16;
    float f;
    __builtin_memcpy(&f, &v, 4);
    return f;
}

__device__ __forceinline__ u16 f2bf16u(float f) {
    __hip_bfloat16 b = __float2bfloat16(f);   // RNE
    u16 u;
    __builtin_memcpy(&u, &b, 2);
    return u;
}

__device__ __forceinline__ float fast_sigmoid(float x) {
    return 1.0f / (1.0f + __expf(-x));
}

__device__ __forceinline__ float fast_tanh(float x) {
    float e = __expf(-2.0f * fabsf(x));     // in (0,1], never overflows
    float r = (1.0f - e) / (1.0f + e);
    return x < 0.0f ? -r : r;
}

// direct global->LDS, 16 B per lane; LDS dest = wave-uniform base + lane*16
__device__ __forceinline__ void gload16(const u16* g, u16* l) {
    __builtin_amdgcn_global_load_lds(GLOBAL_AS((u16*)g), LDS_AS(l), 16, 0, 0);
}

// -------- probe: classify input storage dtype ------------------------------
__global__ void probe_dtype(const unsigned* __restrict__ x, int* __restrict__ flag) {
    const int lane = threadIdx.x;
    const unsigned lo = x[lane] & 0xFFFFu;
    const unsigned e = (lo >> 7) & 0xFFu;
    const bool sane = (e >= 100u && e <= 140u) || (lo == 0u);
    const unsigned long long m = __ballot(sane);
    if (lane == 0) *flag = (__popcll(m) >= 48) ? 1 : 0;   // 1 = bf16, 0 = fp32
}

// -------- prep: pack W into Wt[g][n][k] (bf16), n-major, k = [Wx ; Wh] -----
__global__ void pack_weights(const void* __restrict__ Wxi, const void* __restrict__ Whi,
                             const void* __restrict__ Wxc, const void* __restrict__ Whc,
                             const void* __restrict__ Wxo, const void* __restrict__ Who,
                             const int* __restrict__ flag, u16* __restrict__ Wt)
{
    __shared__ u16 tile[32][33];
    const bool isbf = (*flag != 0);
    const int g = blockIdx.z >> 1, half = blockIdx.z & 1;
    const void* src;
    if (g == 0)      src = half ? Whi : Wxi;
    else if (g == 1) src = half ? Whc : Wxc;
    else             src = half ? Who : Wxo;
    const int kk = blockIdx.y * 32, nn = blockIdx.x * 32;
    const int tx = threadIdx.x, ty = threadIdx.y;
    if (isbf) {
        const u16* s = (const u16*)src;
#pragma unroll
        for (int i2 = 0; i2 < 4; ++i2)
            tile[ty + 8 * i2][tx] = s[(kk + ty + 8 * i2) * 512 + nn + tx];
    } else {
        const float* s = (const float*)src;
#pragma unroll
        for (int i2 = 0; i2 < 4; ++i2)
            tile[ty + 8 * i2][tx] = f2bf16u(s[(kk + ty + 8 * i2) * 512 + nn + tx]);
    }
    __syncthreads();
#pragma unroll
    for (int i2 = 0; i2 < 4; ++i2)
        Wt[(long)g * 524288 + (long)(nn + ty + 8 * i2) * 1024 + half * 512 + kk + tx]
            = tile[tx][ty + 8 * i2];
}

// -------- prep: pack U = [x | h] as bf16 [32768][1024], k-contiguous -------
__global__ __launch_bounds__(256) void pack_u(
    const void* __restrict__ x, const void* __restrict__ h,
    const int* __restrict__ flag, u16* __restrict__ U)
{
    const bool isbf = (*flag != 0);
    const long stride = (long)gridDim.x * blockDim.x;
    for (long t = (long)blockIdx.x * blockDim.x + threadIdx.x;
         t < (U_ELEMS >> 3); t += stride) {
        const long e = t << 3;                 // element index into U
        const int r = (int)(e >> 10);
        const int k = (int)(e & 1023);
        const void* src = (k < 512) ? x : h;   // 8 | 512 -> branch uniform per chunk
        const long so = (long)r * 512 + (k & 511);
        u16x8 o;
        if (isbf) {
            o = *(const u16x8*)((const u16*)src + so);
        } else {
            const float* s = (const float*)src + so;
            f32x4 p0 = *(const f32x4*)s;
            f32x4 p1 = *(const f32x4*)(s + 4);
#pragma unroll
            for (int j = 0; j < 4; ++j) {
                o[j] = f2bf16u(p0[j]);
                o[4 + j] = f2bf16u(p1[j]);
            }
        }
        *(u16x8*)(U + e) = o;
    }
}

// -------- main v2: bf16 GEMM, BK=64, global_load_lds, swizzled LDS --------
// grid 2048 (flat): swz -> m-tile (128 rows) x n-tile (64 cols). 256 thr.
// LDS rows are 128 B (8 x 16B chunks); swizzle: stored chunk p holds global
// chunk k2 = p ^ (row&7). 2-way bank aliasing only (free).
__global__ __launch_bounds__(256, 2) void lstm_gemm_v2(
    const u16* __restrict__ U, const u16* __restrict__ Wt,
    const void* __restrict__ bxi, const void* __restrict__ bxc,
    const void* __restrict__ bxo, const int* __restrict__ flag,
    void* __restrict__ out)
{
    __shared__ __align__(16) u16 As[128 * 64];      // 16 KB, [row][8 chunks swz]
    __shared__ __align__(16) u16 Bs[3 * 64 * 64];   // 24 KB, [g][n][8 chunks swz]

    const bool isbf = (*flag != 0);
    const int tid    = threadIdx.x;
    const int lane   = tid & 63;
    const int wave   = tid >> 6;
    const int wave_m = wave & 1;
    const int wave_n = wave >> 1;

    // XCD-chunked swizzle: XCD x owns m-panels [32x, 32x+32), all 8 n-tiles
    // of a panel launch consecutively on that XCD -> A panel L2-resident.
    const int swz = (blockIdx.x & 7) * 256 + (blockIdx.x >> 3);
    const int m0 = (swz >> 3) * 128;
    const int n0 = (swz & 7) * 64;

    // ---- staging sources (pre-swizzled per-lane global addresses) --------
    // chunk c (1 KB) covers 8 rows; lane l -> row c*8 + (l>>3), LDS slot l&7,
    // so it must fetch global chunk k2 = (l&7) ^ (l>>3).
    const int srow = lane >> 3;
    const int sk2  = (lane & 7) ^ srow;
    const u16* a_src[4];
#pragma unroll
    for (int j = 0; j < 4; ++j) {
        const int ca = wave * 4 + j;                       // 16 chunks = 128 rows
        a_src[j] = U + (long)(m0 + ca * 8 + srow) * 1024 + sk2 * 8;
    }
    const u16* b_src[6];
#pragma unroll
    for (int q = 0; q < 6; ++q) {
        const int cb = q * 4 + wave;                       // 24 chunks = 3 gates x 64 n
        const int g = cb >> 3;
        const int nrow = (cb & 7) * 8 + srow;
        b_src[q] = Wt + (long)g * 524288 + (long)(n0 + nrow) * 1024 + sk2 * 8;
    }

    // ---- fragment ds_read offsets (u16 index), kk=0; kk=1 is idx^32 ------
    // reader wants global chunk k2 = kk*4 + (lane>>4) at row -> slot k2^(row&7)
    int a_off[4];
#pragma unroll
    for (int mt = 0; mt < 4; ++mt) {
        const int row = wave_m * 64 + mt * 16 + (lane & 15);
        const int p = (lane >> 4) ^ (row & 7);
        a_off[mt] = row * 64 + p * 8;
    }
    int b_off[3][2];
#pragma unroll
    for (int g = 0; g < 3; ++g)
#pragma unroll
        for (int nt = 0; nt < 2; ++nt) {
            const int row = wave_n * 32 + nt * 16 + (lane & 15);
            const int p = (lane >> 4) ^ (row & 7);
            b_off[g][nt] = g * 4096 + row * 64 + p * 8;
        }

    f32x4 acc[3][4][2];
    const f32x4 zero = {0.f, 0.f, 0.f, 0.f};
#pragma unroll
    for (int g = 0; g < 3; ++g)
#pragma unroll
        for (int mt = 0; mt < 4; ++mt)
#pragma unroll
            for (int nt = 0; nt < 2; ++nt)
                acc[g][mt][nt] = zero;

    // ---- K loop: 16 iters of BK=64, single LDS buffer, 2 barriers/iter ---
    for (int k0 = 0; k0 < K_DIM; k0 += 64) {
        __syncthreads();                      // prior iter's ds_reads retired
#pragma unroll
        for (int j = 0; j < 4; ++j)
            gload16(a_src[j] + k0, &As[(wave * 4 + j) * 512]);
#pragma unroll
        for (int q = 0; q < 6; ++q)
            gload16(b_src[q] + k0, &Bs[(q * 4 + wave) * 512]);
        __syncthreads();                      // vmcnt(0) drain: tile staged

#pragma unroll
        for (int kk = 0; kk < 2; ++kk) {
            const int kx = kk * 32;           // chunk^4 <=> u16 idx ^ 32
            bf16x8 af[4];
#pragma unroll
            for (int mt = 0; mt < 4; ++mt)
                af[mt] = *(const bf16x8*)&As[a_off[mt] ^ kx];
            bf16x8 bfr[3][2];
#pragma unroll
            for (int g = 0; g < 3; ++g)
#pragma unroll
                for (int nt = 0; nt < 2; ++nt)
                    bfr[g][nt] = *(const bf16x8*)&Bs[b_off[g][nt] ^ kx];
#pragma unroll
            for (int g = 0; g < 3; ++g)
#pragma unroll
                for (int mt = 0; mt < 4; ++mt)
#pragma unroll
                    for (int nt = 0; nt < 2; ++nt)
                        acc[g][mt][nt] = __builtin_amdgcn_mfma_f32_16x16x32_bf16(
                            af[mt], bfr[g][nt], acc[g][mt][nt], 0, 0, 0);
        }
    }

    // ---- epilogue: bias + activations + store (dtype-matched) -------------
    // C/D layout: col = lane&15, row = (lane>>4)*4 + reg  [m89/m91 verified]
    const int colbase = n0 + wave_n * 32 + (lane & 15);
    float bi[2], bc[2], bo[2];
#pragma unroll
    for (int nt = 0; nt < 2; ++nt) {
        const int col = colbase + nt * 16;
        if (isbf) {
            bi[nt] = bf2f(((const u16*)bxi)[col]);
            bc[nt] = bf2f(((const u16*)bxc)[col]);
            bo[nt] = bf2f(((const u16*)bxo)[col]);
        } else {
            bi[nt] = ((const float*)bxi)[col];
            bc[nt] = ((const float*)bxc)[col];
            bo[nt] = ((const float*)bxo)[col];
        }
    }

    const int rowbase = m0 + wave_m * 64 + (lane >> 4) * 4;
#pragma unroll
    for (int mt = 0; mt < 4; ++mt)
#pragma unroll
        for (int nt = 0; nt < 2; ++nt)
#pragma unroll
            for (int r = 0; r < 4; ++r) {
                const int row = rowbase + mt * 16 + r;
                const int col = colbase + nt * 16;
                const float iv = fast_sigmoid(acc[0][mt][nt][r] + bi[nt]);
                const float cv = iv * fast_tanh(acc[1][mt][nt][r] + bc[nt]);
                const float ov = fast_sigmoid(acc[2][mt][nt][r] + bo[nt]);
                const float hv = ov * fast_tanh(cv);
                const long idx = (long)row * 512 + col;
                if (isbf) {
                    ((u16*)out)[idx]            = f2bf16u(hv);
                    ((u16*)out)[BH_ELEMS + idx] = f2bf16u(cv);
                } else {
                    ((float*)out)[idx]            = hv;
                    ((float*)out)[BH_ELEMS + idx] = cv;
                }
            }
}

// -------- fallback (R2 kernel, verbatim): used if ws can't hold U ---------
__global__ __launch_bounds__(256, 2) void lstm_gemm_fb(
    const void* __restrict__ x, const void* __restrict__ h,
    const u16* __restrict__ Wt,
    const void* __restrict__ bxi, const void* __restrict__ bxc,
    const void* __restrict__ bxo, const int* __restrict__ flag,
    void* __restrict__ out)
{
    __shared__ __align__(16) u16 As[128 * 32];
    __shared__ __align__(16) u16 Bs[3 * 64 * 32];

    const bool isbf = (*flag != 0);
    const int tid    = threadIdx.x;
    const int lane   = tid & 63;
    const int wave   = tid >> 6;
    const int wave_m = wave & 1;
    const int wave_n = wave >> 1;
    const int m0 = blockIdx.y * 128;
    const int n0 = blockIdx.x * 64;

    const int trow = tid >> 2, tkc = (tid & 3) * 8;
    const long a_g0 = (long)(m0 + trow)      * 512 + tkc;
    const long a_g1 = (long)(m0 + 64 + trow) * 512 + tkc;
    const int  a_l0 = tid * 8;
    const int  a_l1 = 2048 + tid * 8;
    long b_g[3];
#pragma unroll
    for (int q = 0; q < 3; ++q)
        b_g[q] = (long)q * 524288 + (long)(n0 + trow) * 1024 + tkc;

    int a_ld[4];
#pragma unroll
    for (int mt = 0; mt < 4; ++mt)
        a_ld[mt] = (wave_m * 64 + mt * 16 + (lane & 15)) * 32 + (lane >> 4) * 8;
    int b_ld[3][2];
#pragma unroll
    for (int g = 0; g < 3; ++g)
#pragma unroll
        for (int nt = 0; nt < 2; ++nt)
            b_ld[g][nt] = g * 2048 + (wave_n * 32 + nt * 16 + (lane & 15)) * 32 + (lane >> 4) * 8;

    f32x4 acc[3][4][2];
    const f32x4 zero = {0.f, 0.f, 0.f, 0.f};
#pragma unroll
    for (int g = 0; g < 3; ++g)
#pragma unroll
        for (int mt = 0; mt < 4; ++mt)
#pragma unroll
            for (int nt = 0; nt < 2; ++nt)
                acc[g][mt][nt] = zero;

    for (int k0 = 0; k0 < K_DIM; k0 += 32) {
        const void* src = (k0 < 512) ? x : h;
        const long kadj = (k0 < 512) ? k0 : (k0 - 512);

        bf16x8 av0, av1, bv[3];
        if (isbf) {
            const u16* s = (const u16*)src + kadj;
            u16x8 t0 = *(const u16x8*)(s + a_g0);
            u16x8 t1 = *(const u16x8*)(s + a_g1);
            __builtin_memcpy(&av0, &t0, 16);
            __builtin_memcpy(&av1, &t1, 16);
        } else {
            const float* s = (const float*)src + kadj;
            f32x4 p0 = *(const f32x4*)(s + a_g0);
            f32x4 p1 = *(const f32x4*)(s + a_g0 + 4);
            f32x4 q0 = *(const f32x4*)(s + a_g1);
            f32x4 q1 = *(const f32x4*)(s + a_g1 + 4);
#pragma unroll
            for (int j = 0; j < 4; ++j) {
                av0[j] = (__bf16)p0[j]; av0[4 + j] = (__bf16)p1[j];
                av1[j] = (__bf16)q0[j]; av1[4 + j] = (__bf16)q1[j];
            }
        }
#pragma unroll
        for (int q = 0; q < 3; ++q) {
            u16x8 t = *(const u16x8*)(Wt + b_g[q] + k0);
            __builtin_memcpy(&bv[q], &t, 16);
        }

        __syncthreads();
        *(bf16x8*)&As[a_l0] = av0;
        *(bf16x8*)&As[a_l1] = av1;
#pragma unroll
        for (int q = 0; q < 3; ++q)
            *(bf16x8*)&Bs[q * 2048 + tid * 8] = bv[q];
        __syncthreads();

        bf16x8 af[4];
#pragma unroll
        for (int mt = 0; mt < 4; ++mt)
            af[mt] = *(const bf16x8*)&As[a_ld[mt]];
        bf16x8 bfr[3][2];
#pragma unroll
        for (int g = 0; g < 3; ++g)
#pragma unroll
            for (int nt = 0; nt < 2; ++nt)
                bfr[g][nt] = *(const bf16x8*)&Bs[b_ld[g][nt]];

#pragma unroll
        for (int g = 0; g < 3; ++g)
#pragma unroll
            for (int mt = 0; mt < 4; ++mt)
#pragma unroll
            for (int nt = 0; nt < 2; ++nt)
                acc[g][mt][nt] = __builtin_amdgcn_mfma_f32_16x16x32_bf16(
                    af[mt], bfr[g][nt], acc[g][mt][nt], 0, 0, 0);
    }

    const int colbase = n0 + wave_n * 32 + (lane & 15);
    float bi[2], bc[2], bo[2];
#pragma unroll
    for (int nt = 0; nt < 2; ++nt) {
        const int col = colbase + nt * 16;
        if (isbf) {
            bi[nt] = bf2f(((const u16*)bxi)[col]);
            bc[nt] = bf2f(((const u16*)bxc)[col]);
            bo[nt] = bf2f(((const u16*)bxo)[col]);
        } else {
            bi[nt] = ((const float*)bxi)[col];
            bc[nt] = ((const float*)bxc)[col];
            bo[nt] = ((const float*)bxo)[col];
        }
    }

    const int rowbase = m0 + wave_m * 64 + (lane >> 4) * 4;
#pragma unroll
    for (int mt = 0; mt < 4; ++mt)
#pragma unroll
        for (int nt = 0; nt < 2; ++nt)
#pragma unroll
            for (int r = 0; r < 4; ++r) {
                const int row = rowbase + mt * 16 + r;
                const int col = colbase + nt * 16;
                const float iv = fast_sigmoid(acc[0][mt][nt][r] + bi[nt]);
                const float cv = iv * fast_tanh(acc[1][mt][nt][r] + bc[nt]);
                const float ov = fast_sigmoid(acc[2][mt][nt][r] + bo[nt]);
                const float hv = ov * fast_tanh(cv);
                const long idx = (long)row * 512 + col;
                if (isbf) {
                    ((u16*)out)[idx]            = f2bf16u(hv);
                    ((u16*)out)[BH_ELEMS + idx] = f2bf16u(cv);
                } else {
                    ((float*)out)[idx]            = hv;
                    ((float*)out)[BH_ELEMS + idx] = cv;
                }
            }
}

extern "C" void kernel_launch(void* const* d_in, const int* in_sizes, int n_in,
                              void* d_out, int out_size, void* d_ws, size_t ws_size,
                              hipStream_t stream) {
    const void* x   = d_in[0];
    const void* h   = d_in[1];
    // d_in[2] = c_prev: dead in reference math, not read.
    const void* Wxi = d_in[3];
    const void* bxi = d_in[4];
    const void* Whi = d_in[5];
    // d_in[6..8] = Wxf/bxf/Whf: f gate is computed-then-discarded -> skipped.
    const void* Wxc = d_in[9];
    const void* bxc = d_in[10];
    const void* Whc = d_in[11];
    const void* Wxo = d_in[12];
    const void* bxo = d_in[13];
    const void* Who = d_in[14];

    int* flag = (int*)d_ws;                       // [0,4): dtype flag
    u16* Wt   = (u16*)((char*)d_ws + 256);        // 3 MB packed weights (bf16)
    const size_t need = 256 + (size_t)WT_BYTES + U_BYTES;   // ~70.3 MB

    probe_dtype<<<1, 64, 0, stream>>>((const unsigned*)x, flag);
    pack_weights<<<dim3(16, 16, 6), dim3(32, 8), 0, stream>>>(
        Wxi, Whi, Wxc, Whc, Wxo, Who, flag, Wt);

    if (ws_size >= need) {
        u16* U = (u16*)((char*)d_ws + 256 + WT_BYTES);   // 64 MB bf16 [x|h]
        pack_u<<<dim3(4096), dim3(256), 0, stream>>>(x, h, flag, U);
        lstm_gemm_v2<<<dim3(2048), dim3(256), 0, stream>>>(
            U, Wt, bxi, bxc, bxo, flag, d_out);
    } else {
        lstm_gemm_fb<<<dim3(8, 256), dim3(256), 0, stream>>>(
            x, h, Wt, bxi, bxc, bxo, flag, d_out);
    }
}

// Round 3
// 380.589 us; speedup vs baseline: 1.1910x; 1.0265x over previous
//
#include <hip/hip_runtime.h>
#include <hip/hip_bf16.h>

// LSTM_single_task: B=32768, I=H=512. Live math: 3 gate GEMMs (i,c,o) over
// u=[x,h] (K=1024), fused activations. f-gate and c_prev are dead code.
//
// R5: resubmit of R4 (R4 bench died to container infra failure, not kernel;
// code re-audited: LDS/global indexing in-range, barriers uniform, 80 KB
// static LDS legal on gfx950). vs R3 (390 us total; gemm 128 us, MfmaUtil
// 36%, 0 bank conflicts, FETCH 76 MB = ideal):
//  - gemm_v3: double-buffered LDS (80 KB, 2 blocks/CU), prefetch STAGE(t+1)
//    issued BEFORE compute of tile t, ONE barrier per BK=64 step (16 vs 32).
//    The vmcnt(0) drain at the barrier lands AFTER the compute phase ->
//    global_load_lds latency hidden (T3 minimum-2-phase template).
//  - s_setprio dropped vs R4: T5 is null on 2-phase lockstep (m190/m230).
//  - prep: probe + pack_weights + pack_u fused into one kernel; every block
//    (and gemm) derives the dtype flag from x's first 64 words wave-uniformly
//    -> 2 dispatches total, no flag round-trip through memory.
//  - epilogue: v_rcp_f32 instead of precise float divide (4 divides/output).
//  - Fallback to the R2-style kernel if ws_size < 70.3 MB (U doesn't fit).

typedef unsigned short u16;
typedef u16 u16x8 __attribute__((ext_vector_type(8)));
typedef __bf16 bf16x8 __attribute__((ext_vector_type(8)));
typedef float f32x4 __attribute__((ext_vector_type(4)));

#define B_DIM 32768
#define H_DIM 512
#define K_DIM 1024
#define BH_ELEMS (B_DIM * H_DIM)          // 16,777,216
#define U_ELEMS ((long)B_DIM * K_DIM)     // 33,554,432
#define WT_BYTES ((size_t)(3u * 512u * 1024u * 2u)) // 3,145,728
#define U_BYTES ((size_t)U_ELEMS * 2u)    // 67,108,864

#define GLOBAL_AS(p) ((__attribute__((address_space(1))) void*)(p))
#define LDS_AS(p)    ((__attribute__((address_space(3))) void*)(p))

__device__ __forceinline__ float bf2f(u16 u) {
    unsigned v = ((unsigned)u) << 16;
    float f;
    __builtin_memcpy(&f, &v, 4);
    return f;
}

__device__ __forceinline__ u16 f2bf16u(float f) {
    __hip_bfloat16 b = __float2bfloat16(f);   // RNE
    u16 u;
    __builtin_memcpy(&u, &b, 2);
    return u;
}

__device__ __forceinline__ float fast_rcp(float x) {
    return __builtin_amdgcn_rcpf(x);          // ~1 ulp approx; fine vs bf16 noise
}

__device__ __forceinline__ float fast_sigmoid(float x) {
    return fast_rcp(1.0f + __expf(-x));
}

__device__ __forceinline__ float fast_tanh(float x) {
    float e = __expf(-2.0f * fabsf(x));     // in (0,1], never overflows
    float r = (1.0f - e) * fast_rcp(1.0f + e);
    return x < 0.0f ? -r : r;
}

// Wave-uniform dtype classification from x's first 64 words. fp32 N(0,1):
// low u16 ~ uniform -> ~16% bf16-exponent-sane. bf16: low u16 IS bf16 -> ~100%.
// Every wave reads the same 64 words -> identical result in every block/kernel.
__device__ __forceinline__ bool derive_isbf(const unsigned* __restrict__ x, int tid) {
    const unsigned lo = x[tid & 63] & 0xFFFFu;
    const unsigned e = (lo >> 7) & 0xFFu;
    const bool sane = (e >= 100u && e <= 140u) || (lo == 0u);
    return __popcll(__ballot(sane)) >= 48;
}

// direct global->LDS, 16 B per lane; LDS dest = wave-uniform base + lane*16
__device__ __forceinline__ void gload16(const u16* g, u16* l) {
    __builtin_amdgcn_global_load_lds(GLOBAL_AS((u16*)g), LDS_AS(l), 16, 0, 0);
}

// -------- prep: pack_weights (blocks 0..1535) + pack_u (blocks 1536..5631) --
// pack_weights: Wt[g][n][k] bf16, n-major, k = [Wx ; Wh]; 32x32 LDS transpose.
// pack_u: U = [x | h] as bf16 [32768][1024], k-contiguous.
__global__ __launch_bounds__(256) void prep(
    const void* __restrict__ x, const void* __restrict__ h,
    const void* __restrict__ Wxi, const void* __restrict__ Whi,
    const void* __restrict__ Wxc, const void* __restrict__ Whc,
    const void* __restrict__ Wxo, const void* __restrict__ Who,
    u16* __restrict__ Wt, u16* __restrict__ U)
{
    __shared__ u16 tile[32][33];
    const int tid = threadIdx.x;
    const bool isbf = derive_isbf((const unsigned*)x, tid);
    const int bid = blockIdx.x;

    if (bid < 1536) {
        // ---- pack_weights ------------------------------------------------
        const int bz = bid >> 8, rem = bid & 255;
        const int by = rem >> 4, bx = rem & 15;
        const int g = bz >> 1, half = bz & 1;
        const void* src;
        if (g == 0)      src = half ? Whi : Wxi;
        else if (g == 1) src = half ? Whc : Wxc;
        else             src = half ? Who : Wxo;
        const int kk = by * 32, nn = bx * 32;
        const int tx = tid & 31, ty = tid >> 5;
        if (isbf) {
            const u16* s = (const u16*)src;
#pragma unroll
            for (int i2 = 0; i2 < 4; ++i2)
                tile[ty + 8 * i2][tx] = s[(kk + ty + 8 * i2) * 512 + nn + tx];
        } else {
            const float* s = (const float*)src;
#pragma unroll
            for (int i2 = 0; i2 < 4; ++i2)
                tile[ty + 8 * i2][tx] = f2bf16u(s[(kk + ty + 8 * i2) * 512 + nn + tx]);
        }
        __syncthreads();
#pragma unroll
        for (int i2 = 0; i2 < 4; ++i2)
            Wt[(long)g * 524288 + (long)(nn + ty + 8 * i2) * 1024 + half * 512 + kk + tx]
                = tile[tx][ty + 8 * i2];
    } else {
        // ---- pack_u ------------------------------------------------------
        const long stride = 4096L * 256L;
        for (long t = (long)(bid - 1536) * 256 + tid;
             t < (U_ELEMS >> 3); t += stride) {
            const long e = t << 3;                 // element index into U
            const int r = (int)(e >> 10);
            const int k = (int)(e & 1023);
            const void* src = (k < 512) ? x : h;   // chunk-uniform
            const long so = (long)r * 512 + (k & 511);
            u16x8 o;
            if (isbf) {
                o = *(const u16x8*)((const u16*)src + so);
            } else {
                const float* s = (const float*)src + so;
                f32x4 p0 = *(const f32x4*)s;
                f32x4 p1 = *(const f32x4*)(s + 4);
#pragma unroll
                for (int j = 0; j < 4; ++j) {
                    o[j] = f2bf16u(p0[j]);
                    o[4 + j] = f2bf16u(p1[j]);
                }
            }
            *(u16x8*)(U + e) = o;
        }
    }
}

// -------- main v3: bf16 GEMM, BK=64, dbuf prefetch, 1 barrier/step --------
// grid 2048 (flat): swz -> m-tile (128 rows) x n-tile (64 cols). 256 thr.
// LDS rows are 128 B (8 x 16B chunks); swizzle: stored chunk p holds global
// chunk k2 = p ^ (row&7). 2-way bank aliasing only (free).
__global__ __launch_bounds__(256, 2) void lstm_gemm_v3(
    const void* __restrict__ x,                   // only for dtype probe
    const u16* __restrict__ U, const u16* __restrict__ Wt,
    const void* __restrict__ bxi, const void* __restrict__ bxc,
    const void* __restrict__ bxo, void* __restrict__ out)
{
    __shared__ __align__(16) u16 As[2][128 * 64];    // 2 x 16 KB
    __shared__ __align__(16) u16 Bs[2][3 * 64 * 64]; // 2 x 24 KB

    const int tid    = threadIdx.x;
    const bool isbf  = derive_isbf((const unsigned*)x, tid);
    const int lane   = tid & 63;
    const int wave   = tid >> 6;
    const int wave_m = wave & 1;
    const int wave_n = wave >> 1;

    // XCD-chunked swizzle: XCD x owns m-panels [32x, 32x+32); the 8 n-tiles
    // of a panel launch consecutively on that XCD -> A panel L2-resident.
    const int swz = (blockIdx.x & 7) * 256 + (blockIdx.x >> 3);
    const int m0 = (swz >> 3) * 128;
    const int n0 = (swz & 7) * 64;

    // ---- staging sources (pre-swizzled per-lane global addresses) --------
    // chunk c (1 KB) covers 8 rows; lane l -> row c*8 + (l>>3), LDS slot l&7,
    // so it must fetch global chunk k2 = (l&7) ^ (l>>3).
    const int srow = lane >> 3;
    const int sk2  = (lane & 7) ^ srow;
    const u16* a_src[4];
#pragma unroll
    for (int j = 0; j < 4; ++j) {
        const int ca = wave * 4 + j;                       // 16 chunks = 128 rows
        a_src[j] = U + (long)(m0 + ca * 8 + srow) * 1024 + sk2 * 8;
    }
    const u16* b_src[6];
#pragma unroll
    for (int q = 0; q < 6; ++q) {
        const int cb = q * 4 + wave;                       // 24 chunks = 3 gates x 64 n
        const int g = cb >> 3;
        const int nrow = (cb & 7) * 8 + srow;
        b_src[q] = Wt + (long)g * 524288 + (long)(n0 + nrow) * 1024 + sk2 * 8;
    }

#define STAGE_TILE(bi, kofs) do {                                         \
    _Pragma("unroll")                                                     \
    for (int j_ = 0; j_ < 4; ++j_)                                        \
        gload16(a_src[j_] + (kofs), &As[bi][(wave * 4 + j_) * 512]);      \
    _Pragma("unroll")                                                     \
    for (int q_ = 0; q_ < 6; ++q_)                                        \
        gload16(b_src[q_] + (kofs), &Bs[bi][(q_ * 4 + wave) * 512]);      \
} while (0)

    // ---- fragment ds_read offsets (u16 index), kk=0; kk=1 is idx^32 ------
    // reader wants global chunk k2 = kk*4 + (lane>>4) at row -> slot k2^(row&7)
    int a_off[4];
#pragma unroll
    for (int mt = 0; mt < 4; ++mt) {
        const int row = wave_m * 64 + mt * 16 + (lane & 15);
        const int p = (lane >> 4) ^ (row & 7);
        a_off[mt] = row * 64 + p * 8;
    }
    int b_off[3][2];
#pragma unroll
    for (int g = 0; g < 3; ++g)
#pragma unroll
        for (int nt = 0; nt < 2; ++nt) {
            const int row = wave_n * 32 + nt * 16 + (lane & 15);
            const int p = (lane >> 4) ^ (row & 7);
            b_off[g][nt] = g * 4096 + row * 64 + p * 8;
        }

    f32x4 acc[3][4][2];
    const f32x4 zero = {0.f, 0.f, 0.f, 0.f};
#pragma unroll
    for (int g = 0; g < 3; ++g)
#pragma unroll
        for (int mt = 0; mt < 4; ++mt)
#pragma unroll
            for (int nt = 0; nt < 2; ++nt)
                acc[g][mt][nt] = zero;

    // ---- K loop: 16 steps of BK=64, double-buffered, 1 barrier/step ------
    // Iter t: issue STAGE(t+1) -> compute tile t -> __syncthreads() (its
    // implicit vmcnt(0)+lgkmcnt(0) drain lands AFTER the compute phase, so
    // the prefetch latency is hidden; it also fences buffer reuse: buffer
    // cur^1 was last READ at step t-1 and retired at the t-1 barrier).
    STAGE_TILE(0, 0);
    __syncthreads();                          // tile 0 staged
#pragma unroll
    for (int t = 0; t < 16; ++t) {
        const int cur = t & 1;
        if (t < 15) STAGE_TILE(cur ^ 1, (t + 1) * 64);

#pragma unroll
        for (int kk = 0; kk < 2; ++kk) {
            const int kx = kk * 32;           // chunk^4 <=> u16 idx ^ 32
            bf16x8 af[4];
#pragma unroll
            for (int mt = 0; mt < 4; ++mt)
                af[mt] = *(const bf16x8*)&As[cur][a_off[mt] ^ kx];
            bf16x8 bfr[3][2];
#pragma unroll
            for (int g = 0; g < 3; ++g)
#pragma unroll
                for (int nt = 0; nt < 2; ++nt)
                    bfr[g][nt] = *(const bf16x8*)&Bs[cur][b_off[g][nt] ^ kx];

#pragma unroll
            for (int g = 0; g < 3; ++g)
#pragma unroll
                for (int mt = 0; mt < 4; ++mt)
#pragma unroll
                    for (int nt = 0; nt < 2; ++nt)
                        acc[g][mt][nt] = __builtin_amdgcn_mfma_f32_16x16x32_bf16(
                            af[mt], bfr[g][nt], acc[g][mt][nt], 0, 0, 0);
        }
        if (t < 15) __syncthreads();          // prefetch landed + reads retired
    }
#undef STAGE_TILE

    // ---- epilogue: bias + activations + store (dtype-matched) -------------
    // C/D layout: col = lane&15, row = (lane>>4)*4 + reg  [m89/m91 verified]
    const int colbase = n0 + wave_n * 32 + (lane & 15);
    float bi[2], bc[2], bo[2];
#pragma unroll
    for (int nt = 0; nt < 2; ++nt) {
        const int col = colbase + nt * 16;
        if (isbf) {
            bi[nt] = bf2f(((const u16*)bxi)[col]);
            bc[nt] = bf2f(((const u16*)bxc)[col]);
            bo[nt] = bf2f(((const u16*)bxo)[col]);
        } else {
            bi[nt] = ((const float*)bxi)[col];
            bc[nt] = ((const float*)bxc)[col];
            bo[nt] = ((const float*)bxo)[col];
        }
    }

    const int rowbase = m0 + wave_m * 64 + (lane >> 4) * 4;
#pragma unroll
    for (int mt = 0; mt < 4; ++mt)
#pragma unroll
        for (int nt = 0; nt < 2; ++nt)
#pragma unroll
            for (int r = 0; r < 4; ++r) {
                const int row = rowbase + mt * 16 + r;
                const int col = colbase + nt * 16;
                const float iv = fast_sigmoid(acc[0][mt][nt][r] + bi[nt]);
                const float cv = iv * fast_tanh(acc[1][mt][nt][r] + bc[nt]);
                const float ov = fast_sigmoid(acc[2][mt][nt][r] + bo[nt]);
                const float hv = ov * fast_tanh(cv);
                const long idx = (long)row * 512 + col;
                if (isbf) {
                    ((u16*)out)[idx]            = f2bf16u(hv);
                    ((u16*)out)[BH_ELEMS + idx] = f2bf16u(cv);
                } else {
                    ((float*)out)[idx]            = hv;
                    ((float*)out)[BH_ELEMS + idx] = cv;
                }
            }
}

// -------- fallback (R2-style): used if ws can't hold U --------------------
__global__ __launch_bounds__(256, 2) void lstm_gemm_fb(
    const void* __restrict__ x, const void* __restrict__ h,
    const u16* __restrict__ Wt,
    const void* __restrict__ bxi, const void* __restrict__ bxc,
    const void* __restrict__ bxo, void* __restrict__ out)
{
    __shared__ __align__(16) u16 As[128 * 32];
    __shared__ __align__(16) u16 Bs[3 * 64 * 32];

    const int tid    = threadIdx.x;
    const bool isbf  = derive_isbf((const unsigned*)x, tid);
    const int lane   = tid & 63;
    const int wave   = tid >> 6;
    const int wave_m = wave & 1;
    const int wave_n = wave >> 1;
    const int m0 = blockIdx.y * 128;
    const int n0 = blockIdx.x * 64;

    const int trow = tid >> 2, tkc = (tid & 3) * 8;
    const long a_g0 = (long)(m0 + trow)      * 512 + tkc;
    const long a_g1 = (long)(m0 + 64 + trow) * 512 + tkc;
    const int  a_l0 = tid * 8;
    const int  a_l1 = 2048 + tid * 8;
    long b_g[3];
#pragma unroll
    for (int q = 0; q < 3; ++q)
        b_g[q] = (long)q * 524288 + (long)(n0 + trow) * 1024 + tkc;

    int a_ld[4];
#pragma unroll
    for (int mt = 0; mt < 4; ++mt)
        a_ld[mt] = (wave_m * 64 + mt * 16 + (lane & 15)) * 32 + (lane >> 4) * 8;
    int b_ld[3][2];
#pragma unroll
    for (int g = 0; g < 3; ++g)
#pragma unroll
        for (int nt = 0; nt < 2; ++nt)
            b_ld[g][nt] = g * 2048 + (wave_n * 32 + nt * 16 + (lane & 15)) * 32 + (lane >> 4) * 8;

    f32x4 acc[3][4][2];
    const f32x4 zero = {0.f, 0.f, 0.f, 0.f};
#pragma unroll
    for (int g = 0; g < 3; ++g)
#pragma unroll
        for (int mt = 0; mt < 4; ++mt)
#pragma unroll
            for (int nt = 0; nt < 2; ++nt)
                acc[g][mt][nt] = zero;

    for (int k0 = 0; k0 < K_DIM; k0 += 32) {
        const void* src = (k0 < 512) ? x : h;
        const long kadj = (k0 < 512) ? k0 : (k0 - 512);

        bf16x8 av0, av1, bv[3];
        if (isbf) {
            const u16* s = (const u16*)src + kadj;
            u16x8 t0 = *(const u16x8*)(s + a_g0);
            u16x8 t1 = *(const u16x8*)(s + a_g1);
            __builtin_memcpy(&av0, &t0, 16);
            __builtin_memcpy(&av1, &t1, 16);
        } else {
            const float* s = (const float*)src + kadj;
            f32x4 p0 = *(const f32x4*)(s + a_g0);
            f32x4 p1 = *(const f32x4*)(s + a_g0 + 4);
            f32x4 q0 = *(const f32x4*)(s + a_g1);
            f32x4 q1 = *(const f32x4*)(s + a_g1 + 4);
#pragma unroll
            for (int j = 0; j < 4; ++j) {
                av0[j] = (__bf16)p0[j]; av0[4 + j] = (__bf16)p1[j];
                av1[j] = (__bf16)q0[j]; av1[4 + j] = (__bf16)q1[j];
            }
        }
#pragma unroll
        for (int q = 0; q < 3; ++q) {
            u16x8 t = *(const u16x8*)(Wt + b_g[q] + k0);
            __builtin_memcpy(&bv[q], &t, 16);
        }

        __syncthreads();
        *(bf16x8*)&As[a_l0] = av0;
        *(bf16x8*)&As[a_l1] = av1;
#pragma unroll
        for (int q = 0; q < 3; ++q)
            *(bf16x8*)&Bs[q * 2048 + tid * 8] = bv[q];
        __syncthreads();

        bf16x8 af[4];
#pragma unroll
        for (int mt = 0; mt < 4; ++mt)
            af[mt] = *(const bf16x8*)&As[a_ld[mt]];
        bf16x8 bfr[3][2];
#pragma unroll
        for (int g = 0; g < 3; ++g)
#pragma unroll
            for (int nt = 0; nt < 2; ++nt)
                bfr[g][nt] = *(const bf16x8*)&Bs[b_ld[g][nt]];

#pragma unroll
        for (int g = 0; g < 3; ++g)
#pragma unroll
            for (int mt = 0; mt < 4; ++mt)
#pragma unroll
            for (int nt = 0; nt < 2; ++nt)
                acc[g][mt][nt] = __builtin_amdgcn_mfma_f32_16x16x32_bf16(
                    af[mt], bfr[g][nt], acc[g][mt][nt], 0, 0, 0);
    }

    const int colbase = n0 + wave_n * 32 + (lane & 15);
    float bi[2], bc[2], bo[2];
#pragma unroll
    for (int nt = 0; nt < 2; ++nt) {
        const int col = colbase + nt * 16;
        if (isbf) {
            bi[nt] = bf2f(((const u16*)bxi)[col]);
            bc[nt] = bf2f(((const u16*)bxc)[col]);
            bo[nt] = bf2f(((const u16*)bxo)[col]);
        } else {
            bi[nt] = ((const float*)bxi)[col];
            bc[nt] = ((const float*)bxc)[col];
            bo[nt] = ((const float*)bxo)[col];
        }
    }

    const int rowbase = m0 + wave_m * 64 + (lane >> 4) * 4;
#pragma unroll
    for (int mt = 0; mt < 4; ++mt)
#pragma unroll
        for (int nt = 0; nt < 2; ++nt)
#pragma unroll
            for (int r = 0; r < 4; ++r) {
                const int row = rowbase + mt * 16 + r;
                const int col = colbase + nt * 16;
                const float iv = fast_sigmoid(acc[0][mt][nt][r] + bi[nt]);
                const float cv = iv * fast_tanh(acc[1][mt][nt][r] + bc[nt]);
                const float ov = fast_sigmoid(acc[2][mt][nt][r] + bo[nt]);
                const float hv = ov * fast_tanh(cv);
                const long idx = (long)row * 512 + col;
                if (isbf) {
                    ((u16*)out)[idx]            = f2bf16u(hv);
                    ((u16*)out)[BH_ELEMS + idx] = f2bf16u(cv);
                } else {
                    ((float*)out)[idx]            = hv;
                    ((float*)out)[BH_ELEMS + idx] = cv;
                }
            }
}

extern "C" void kernel_launch(void* const* d_in, const int* in_sizes, int n_in,
                              void* d_out, int out_size, void* d_ws, size_t ws_size,
                              hipStream_t stream) {
    const void* x   = d_in[0];
    const void* h   = d_in[1];
    // d_in[2] = c_prev: dead in reference math, not read.
    const void* Wxi = d_in[3];
    const void* bxi = d_in[4];
    const void* Whi = d_in[5];
    // d_in[6..8] = Wxf/bxf/Whf: f gate is computed-then-discarded -> skipped.
    const void* Wxc = d_in[9];
    const void* bxc = d_in[10];
    const void* Whc = d_in[11];
    const void* Wxo = d_in[12];
    const void* bxo = d_in[13];
    const void* Who = d_in[14];

    u16* Wt = (u16*)d_ws;                         // 3 MB packed weights (bf16)
    const size_t need = WT_BYTES + U_BYTES;       // ~70.3 MB

    if (ws_size >= need) {
        u16* U = (u16*)((char*)d_ws + WT_BYTES);  // 64 MB bf16 [x|h]
        prep<<<dim3(1536 + 4096), dim3(256), 0, stream>>>(
            x, h, Wxi, Whi, Wxc, Whc, Wxo, Who, Wt, U);
        lstm_gemm_v3<<<dim3(2048), dim3(256), 0, stream>>>(
            x, U, Wt, bxi, bxc, bxo, d_out);
    } else {
        prep<<<dim3(1536), dim3(256), 0, stream>>>(     // pack_weights only
            x, h, Wxi, Whi, Wxc, Whc, Wxo, Who, Wt, nullptr);
        lstm_gemm_fb<<<dim3(8, 256), dim3(256), 0, stream>>>(
            x, h, Wt, bxi, bxc, bxo, d_out);
    }
}